// Round 13
// baseline (275.688 us; speedup 1.0000x reference)
//
#include <hip/hip_runtime.h>
#include <math.h>

#define N_NODES  50000
#define N_EDGES  800000
#define N_GRAPHS 5000
#define N_PAIRS  4096
#define F_IN     9
#define H        64
#define NCHUNK   49   // ceil(50000/1024)
#define WPAD     68   // transposed-weight row stride: 272B = 16B-aligned
#define NXCD     8
#define WIN      6250  // N_NODES / NXCD
#define ESTRIPE  3125  // N_EDGES / 256

__device__ __forceinline__ float fast_tanh(float x) {
    float e = __expf(-2.0f * fabsf(x));
    float t = __fdividef(1.0f - e, 1.0f + e);
    return copysignf(t, x);
}

__device__ __forceinline__ float bf2f(unsigned short u) {
    union { unsigned int i; float f; } v; v.i = ((unsigned int)u) << 16; return v.f;
}
__device__ __forceinline__ unsigned short f2bf(float f) {
    union { float f; unsigned int i; } v; v.f = f;
    unsigned int u = v.i;
    return (unsigned short)((u + 0x7FFFu + ((u >> 16) & 1u)) >> 16);
}

__device__ __forceinline__ int lbound(const int* __restrict__ a, int n, int v) {
    int lo = 0, hi = n;
    while (lo < hi) { int m = (lo + hi) >> 1; if (a[m] < v) lo = m + 1; else hi = m; }
    return lo;
}

// ---------------- degree + per-edge rank (atomic return value IS the rank) --------

__global__ void k_deg_rank(const int* __restrict__ dst, int* __restrict__ degi,
                           unsigned char* __restrict__ rank) {
    int i = blockIdx.x * blockDim.x + threadIdx.x;
    if (i < N_EDGES) rank[i] = (unsigned char)atomicAdd(&degi[dst[i]], 1);
}

// ---------------- dis + chunk sums (merged) ----------------

__global__ void k_dis_chunksum(const int* __restrict__ degi, float* __restrict__ dis,
                               int* __restrict__ chunksum) {
    __shared__ int wsum[4];
    int t = threadIdx.x, lane = t & 63, wi = t >> 6;
    int base_i = blockIdx.x * 1024 + t * 4;
    int s = 0;
#pragma unroll
    for (int k = 0; k < 4; ++k) {
        int i = base_i + k;
        if (i < N_NODES) {
            int dg = degi[i];
            s += dg;
            dis[i] = rsqrtf((float)dg + 1.0f);
        }
    }
    for (int o = 32; o > 0; o >>= 1) s += __shfl_down(s, o, 64);
    if (lane == 0) wsum[wi] = s;
    __syncthreads();
    if (t == 0) chunksum[blockIdx.x] = wsum[0] + wsum[1] + wsum[2] + wsum[3];
}

__global__ void k_scanchunks(const int* __restrict__ chunksum, int* __restrict__ chunkbase,
                             int* __restrict__ off) {
    int lane = threadIdx.x;
    int v = (lane < NCHUNK) ? chunksum[lane] : 0;
    int inc = v;
    for (int o = 1; o < 64; o <<= 1) {
        int u = __shfl_up(inc, o, 64);
        if (lane >= o) inc += u;
    }
    if (lane < NCHUNK) chunkbase[lane] = inc - v;
    if (lane == 0) off[N_NODES] = N_EDGES;
}

__global__ void k_scan(const int* __restrict__ degi, const int* __restrict__ chunkbase,
                       int* __restrict__ off) {
    __shared__ int wsum[4];
    int t = threadIdx.x, lane = t & 63, wi = t >> 6;
    int base_i = blockIdx.x * 1024 + t * 4;
    int v[4];
    int s = 0;
#pragma unroll
    for (int k = 0; k < 4; ++k) {
        int i = base_i + k;
        v[k] = (i < N_NODES) ? degi[i] : 0;
        s += v[k];
    }
    int inc = s;
    for (int o = 1; o < 64; o <<= 1) {
        int u = __shfl_up(inc, o, 64);
        if (lane >= o) inc += u;
    }
    if (lane == 63) wsum[wi] = inc;
    __syncthreads();
    int wbase = 0;
    for (int w = 0; w < 4; ++w) if (w < wi) wbase += wsum[w];
    int ex = chunkbase[blockIdx.x] + wbase + inc - s;
#pragma unroll
    for (int k = 0; k < 4; ++k) {
        int i = base_i + k;
        if (i < N_NODES) off[i] = ex;
        ex += v[k];
    }
}

// packed CSR entry: low32 = src byte-offset (src<<7), high32 = norm bits.
// XCD-partitioned: grid 2048; group g = bid&7 writes only dst in [g*WIN,(g+1)*WIN),
// so each XCD's L2 owns one 0.8MB CSR window and scattered stores merge before
// writeback. Each edge stripe is read by 8 blocks (one per group).
__global__ void k_fill(const int* __restrict__ src, const int* __restrict__ dst,
                       const unsigned char* __restrict__ rank,
                       const float* __restrict__ dis, const int* __restrict__ off,
                       unsigned long long* __restrict__ csr_pack) {
    int g  = blockIdx.x & 7;
    int sb = blockIdx.x >> 3;          // 0..255 stripe
    int lo = g * WIN;
    int estart = sb * ESTRIPE;
    int eend   = estart + ESTRIPE;     // exact: 256*3125 = 800000
    for (int e = estart + threadIdx.x; e < eend; e += 256) {
        int d = dst[e];
        if ((unsigned)(d - lo) < (unsigned)WIN) {
            int s = src[e];
            int pos = off[d] + (int)rank[e];
            union { float f; unsigned int i; } nb;
            nb.f = dis[s] * dis[d];
            csr_pack[pos] = (unsigned long long)(unsigned int)(s << 7)
                          | ((unsigned long long)nb.i << 32);
        }
    }
}

// ---------------- layer 1 fused: agg x (9-wide) -> LDS -> mm+bias+tanh -> bf16 -------

__global__ __launch_bounds__(256) void k_layer1(
        const float* __restrict__ x, const int* __restrict__ off,
        const unsigned long long* __restrict__ csr_pack,
        const float* __restrict__ dis, const float* __restrict__ W,
        const float* __restrict__ b, unsigned short* __restrict__ h) {
    __shared__ float sW[F_IN * H];
    __shared__ float sb[H];
    __shared__ float sax[16][F_IN + 1];   // +1 pad
    for (int t = threadIdx.x; t < F_IN * H; t += 256) sW[t] = W[t];
    if (threadIdx.x < H) sb[threadIdx.x] = b[threadIdx.x];

    // phase 1: 16-lane group per node (lanes 0..8 active)
    int g = threadIdx.x >> 4, l = threadIdx.x & 15;
    int node = blockIdx.x * 16 + g;
    if (node < N_NODES && l < F_IN) {
        int beg = off[node], end = off[node + 1];
        float d = dis[node];
        float acc = x[node * F_IN + l] * d * d;
        for (int e = beg; e < end; ++e) {
            unsigned long long p = csr_pack[e];
            int s = (int)((unsigned int)p >> 7);
            union { unsigned int i; float f; } nb; nb.i = (unsigned int)(p >> 32);
            acc += x[s * F_IN + l] * nb.f;
        }
        sax[g][l] = acc;
    }
    __syncthreads();

    // phase 2: 4 rows per wave
    int wi = threadIdx.x >> 6, j = threadIdx.x & 63;
    for (int r = 0; r < 4; ++r) {
        int row = blockIdx.x * 16 + wi * 4 + r;
        if (row >= N_NODES) break;
        float acc = sb[j];
#pragma unroll
        for (int k = 0; k < F_IN; ++k) acc += sax[wi * 4 + r][k] * sW[k * H + j];
        h[row * H + j] = f2bf(fast_tanh(acc));
    }
}

// ---------------- fused layer: gather(h bf16) -> @W + b -> tanh -> bf16 ----------------
// R12 depth-2 pipeline; pack low32 is a pre-shifted byte offset -> no *H mul per edge.

__global__ __launch_bounds__(256) void k_gmm(
        const unsigned short* __restrict__ hin, const int* __restrict__ off,
        const unsigned long long* __restrict__ csr_pack,
        const float* __restrict__ dis, const float* __restrict__ W,
        const float* __restrict__ b, unsigned short* __restrict__ hout) {
    __shared__ float sWt[H][WPAD];   // sWt[j][k] = W[k][j]
    __shared__ float sb[H];
    __shared__ float srow[4][H];
    for (int t = threadIdx.x; t < H * H; t += 256) {
        int k = t >> 6, jx = t & 63;
        sWt[jx][k] = W[t];
    }
    if (threadIdx.x < H) sb[threadIdx.x] = b[threadIdx.x];
    __syncthreads();
    int wi = threadIdx.x >> 6, j = threadIdx.x & 63;
    const char* hbase = (const char*)hin + (j << 1);   // + per-lane feature offset
    for (int it = 0; it < 8; ++it) {
        int node = blockIdx.x * 32 + wi * 8 + it;
        if (node >= N_NODES) break;
        int beg = off[node], end = off[node + 1];
        float d = dis[node];
        float acc = bf2f(hin[node * H + j]) * d * d;
        int nfull = (end - beg) >> 2;
        int e = beg + (nfull << 2);
        const unsigned long long* cp = csr_pack + beg;

        if (nfull >= 2) {
            unsigned long long a0 = cp[0], a1 = cp[1], a2 = cp[2], a3 = cp[3];
            unsigned long long b0 = cp[4], b1 = cp[5], b2 = cp[6], b3 = cp[7];
            float va0 = bf2f(*(const unsigned short*)(hbase + (unsigned int)a0));
            float va1 = bf2f(*(const unsigned short*)(hbase + (unsigned int)a1));
            float va2 = bf2f(*(const unsigned short*)(hbase + (unsigned int)a2));
            float va3 = bf2f(*(const unsigned short*)(hbase + (unsigned int)a3));
            for (int bi = 1; bi < nfull - 1; ++bi) {
                float vb0 = bf2f(*(const unsigned short*)(hbase + (unsigned int)b0));
                float vb1 = bf2f(*(const unsigned short*)(hbase + (unsigned int)b1));
                float vb2 = bf2f(*(const unsigned short*)(hbase + (unsigned int)b2));
                float vb3 = bf2f(*(const unsigned short*)(hbase + (unsigned int)b3));
                const unsigned long long* np = cp + ((bi + 1) << 2);
                unsigned long long c0 = np[0], c1 = np[1], c2 = np[2], c3 = np[3];
                union { unsigned int i; float f; } n0, n1, n2, n3;
                n0.i = (unsigned int)(a0 >> 32); n1.i = (unsigned int)(a1 >> 32);
                n2.i = (unsigned int)(a2 >> 32); n3.i = (unsigned int)(a3 >> 32);
                acc += va0 * n0.f + va1 * n1.f + va2 * n2.f + va3 * n3.f;
                a0 = b0; a1 = b1; a2 = b2; a3 = b3;
                va0 = vb0; va1 = vb1; va2 = vb2; va3 = vb3;
                b0 = c0; b1 = c1; b2 = c2; b3 = c3;
            }
            float vb0 = bf2f(*(const unsigned short*)(hbase + (unsigned int)b0));
            float vb1 = bf2f(*(const unsigned short*)(hbase + (unsigned int)b1));
            float vb2 = bf2f(*(const unsigned short*)(hbase + (unsigned int)b2));
            float vb3 = bf2f(*(const unsigned short*)(hbase + (unsigned int)b3));
            union { unsigned int i; float f; } n0, n1, n2, n3;
            n0.i = (unsigned int)(a0 >> 32); n1.i = (unsigned int)(a1 >> 32);
            n2.i = (unsigned int)(a2 >> 32); n3.i = (unsigned int)(a3 >> 32);
            acc += va0 * n0.f + va1 * n1.f + va2 * n2.f + va3 * n3.f;
            n0.i = (unsigned int)(b0 >> 32); n1.i = (unsigned int)(b1 >> 32);
            n2.i = (unsigned int)(b2 >> 32); n3.i = (unsigned int)(b3 >> 32);
            acc += vb0 * n0.f + vb1 * n1.f + vb2 * n2.f + vb3 * n3.f;
        } else if (nfull == 1) {
            unsigned long long p0 = cp[0], p1 = cp[1], p2 = cp[2], p3 = cp[3];
            float v0 = bf2f(*(const unsigned short*)(hbase + (unsigned int)p0));
            float v1 = bf2f(*(const unsigned short*)(hbase + (unsigned int)p1));
            float v2 = bf2f(*(const unsigned short*)(hbase + (unsigned int)p2));
            float v3 = bf2f(*(const unsigned short*)(hbase + (unsigned int)p3));
            union { unsigned int i; float f; } n0, n1, n2, n3;
            n0.i = (unsigned int)(p0 >> 32); n1.i = (unsigned int)(p1 >> 32);
            n2.i = (unsigned int)(p2 >> 32); n3.i = (unsigned int)(p3 >> 32);
            acc += v0 * n0.f + v1 * n1.f + v2 * n2.f + v3 * n3.f;
        }
        for (; e < end; ++e) {
            unsigned long long p = csr_pack[e];
            union { unsigned int i; float f; } nb; nb.i = (unsigned int)(p >> 32);
            acc += bf2f(*(const unsigned short*)(hbase + (unsigned int)p)) * nb.f;
        }

        srow[wi][j] = acc;          // wave-local write then read: in-order per wave
        float a = sb[j];
#pragma unroll
        for (int kb = 0; kb < H; kb += 4) {
            float4 g4 = *(const float4*)&srow[wi][kb];   // uniform-addr broadcast
            float4 w4 = *(const float4*)&sWt[j][kb];     // per-lane b128
            a += g4.x * w4.x + g4.y * w4.y + g4.z * w4.z + g4.w * w4.w;
        }
        hout[node * H + j] = f2bf(fast_tanh(a));
    }
}

// ---------------- fused MLP + graph pool ----------------

__global__ __launch_bounds__(256) void k_mlp(
        const unsigned short* __restrict__ h, const int* __restrict__ batch,
        const float* __restrict__ fc1w, const float* __restrict__ fc1b,
        const float* __restrict__ fc2w, const float* __restrict__ fc2b,
        const float* __restrict__ fc3w, const float* __restrict__ fc3b,
        float* __restrict__ sums) {
    __shared__ float s1t[H][WPAD];    // s1t[j][k] = fc1w[k*H+j]
    __shared__ float s2t[32][WPAD];   // s2t[j][k] = fc2w[k*32+j]
    __shared__ float s3[32];
    __shared__ float sb1[H];
    __shared__ float sb2[32];
    __shared__ float srow[4][H];
    __shared__ float s1out[4][H];

    for (int t = threadIdx.x; t < H * H; t += 256) {
        int k = t >> 6, jx = t & 63;
        s1t[jx][k] = fc1w[t];
    }
    for (int t = threadIdx.x; t < H * 32; t += 256) {
        int k = t >> 5, jx = t & 31;
        s2t[jx][k] = fc2w[t];
    }
    if (threadIdx.x < 32) s3[threadIdx.x] = fc3w[threadIdx.x];
    if (threadIdx.x < H)  sb1[threadIdx.x] = fc1b[threadIdx.x];
    if (threadIdx.x < 32) sb2[threadIdx.x] = fc2b[threadIdx.x];
    __syncthreads();

    int wi = threadIdx.x >> 6, j = threadIdx.x & 63;
    int jj = j & 31, kb0 = (j >> 5) << 5;
    float b3 = fc3b[0];

    for (int it = 0; it < 8; ++it) {
        int node = blockIdx.x * 32 + wi * 8 + it;
        if (node >= N_NODES) break;

        srow[wi][j] = bf2f(h[node * H + j]);

        float a1 = sb1[j];
#pragma unroll
        for (int kb = 0; kb < H; kb += 4) {
            float4 g4 = *(const float4*)&srow[wi][kb];
            float4 w4 = *(const float4*)&s1t[j][kb];
            a1 += g4.x * w4.x + g4.y * w4.y + g4.z * w4.z + g4.w * w4.w;
        }
        a1 = fast_tanh(a1);
        s1out[wi][j] = a1;

        float a2 = 0.f;
#pragma unroll
        for (int kb = 0; kb < 32; kb += 4) {
            float4 g4 = *(const float4*)&s1out[wi][kb0 + kb];
            float4 w4 = *(const float4*)&s2t[jj][kb0 + kb];
            a2 += g4.x * w4.x + g4.y * w4.y + g4.z * w4.z + g4.w * w4.w;
        }
        a2 += __shfl_xor(a2, 32);             // combine k-halves
        float val = fast_tanh(a2 + sb2[jj]) * s3[jj];
        for (int o = 16; o > 0; o >>= 1) val += __shfl_xor(val, o);
        if (j == 0) atomicAdd(&sums[batch[node]], val + b3);
    }
}

// ---------------- readout: util + pairs (cnt via binary search, merged) ----------------

__global__ void k_finish(const float* __restrict__ sums, const int* __restrict__ batch,
                         const int* __restrict__ ia, const int* __restrict__ ib,
                         float* __restrict__ out_pairs, float* __restrict__ out_util) {
    int i = blockIdx.x * blockDim.x + threadIdx.x;
    if (i < N_GRAPHS) {
        int c = lbound(batch, N_NODES, i + 1) - lbound(batch, N_NODES, i);
        out_util[i] = sums[i] / fmaxf((float)c, 1.0f);
    }
    if (i < N_PAIRS) {
        int a = ia[i], b = ib[i];
        int ca = lbound(batch, N_NODES, a + 1) - lbound(batch, N_NODES, a);
        int cb = lbound(batch, N_NODES, b + 1) - lbound(batch, N_NODES, b);
        float ua = sums[a] / fmaxf((float)ca, 1.0f);
        float ub = sums[b] / fmaxf((float)cb, 1.0f);
        out_pairs[i] = 1.0f / (1.0f + __expf(-(ub - ua)));
    }
}

// ---------------- launch ----------------

extern "C" void kernel_launch(void* const* d_in, const int* in_sizes, int n_in,
                              void* d_out, int out_size, void* d_ws, size_t ws_size,
                              hipStream_t stream) {
    const float* x     = (const float*)d_in[0];
    const int*   ei    = (const int*)d_in[1];
    const int*   batch = (const int*)d_in[2];
    const int*   idx_a = (const int*)d_in[3];
    const int*   idx_b = (const int*)d_in[4];
    const float* W_in  = (const float*)d_in[5];
    const float* b_in  = (const float*)d_in[6];
    const float* W_h   = (const float*)d_in[7];
    const float* b_h   = (const float*)d_in[8];
    const float* W_out = (const float*)d_in[9];
    const float* b_out = (const float*)d_in[10];
    const float* fc1_w = (const float*)d_in[11];
    const float* fc1_b = (const float*)d_in[12];
    const float* fc2_w = (const float*)d_in[13];
    const float* fc2_b = (const float*)d_in[14];
    const float* fc3_w = (const float*)d_in[15];
    const float* fc3_b = (const float*)d_in[16];

    const int* src = ei;
    const int* dst = ei + N_EDGES;

    char* wsb = (char*)d_ws;
    // zero-region (one memset): degi, sums
    int*   degi     = (int*)wsb;    wsb += N_NODES * 4;
    float* sums     = (float*)wsb;  wsb += N_GRAPHS * 4;
    float* dis      = (float*)wsb;  wsb += N_NODES * 4;
    unsigned short* h0 = (unsigned short*)wsb;  wsb += (size_t)N_NODES * H * 2;
    unsigned short* h1 = (unsigned short*)wsb;  wsb += (size_t)N_NODES * H * 2;
    int*   offs     = (int*)wsb;    wsb += (N_NODES + 1) * 4;
    int*   chunksum = (int*)wsb;    wsb += NCHUNK * 4;
    int*   chunkbase= (int*)wsb;    wsb += NCHUNK * 4;
    unsigned char* rank = (unsigned char*)wsb;  wsb += N_EDGES;
    wsb = (char*)(((size_t)wsb + 7) & ~(size_t)7);
    unsigned long long* csr_pack = (unsigned long long*)wsb; wsb += (size_t)N_EDGES * 8;

    float* out_pairs = (float*)d_out;
    float* out_util  = out_pairs + N_PAIRS;

    hipMemsetAsync(degi, 0, (N_NODES + N_GRAPHS) * sizeof(int), stream);

    dim3 blk(256);
    k_deg_rank<<<(N_EDGES + 255) / 256, blk, 0, stream>>>(dst, degi, rank);
    k_dis_chunksum<<<NCHUNK, blk, 0, stream>>>(degi, dis, chunksum);
    k_scanchunks<<<1, 64, 0, stream>>>(chunksum, chunkbase, offs);
    k_scan<<<NCHUNK, blk, 0, stream>>>(degi, chunkbase, offs);
    k_fill<<<256 * NXCD, blk, 0, stream>>>(src, dst, rank, dis, offs, csr_pack);

    // layer 1 fused: agg9 + mm_in
    k_layer1<<<(N_NODES + 15) / 16, blk, 0, stream>>>(x, offs, csr_pack, dis, W_in, b_in, h0);

    const int gmm_blocks = (N_NODES + 31) / 32;
    // layers 2..4: fused gather+matmul+bias+tanh (depth-2 pipelined)
    k_gmm<<<gmm_blocks, blk, 0, stream>>>(h0, offs, csr_pack, dis, W_h, b_h, h1);
    k_gmm<<<gmm_blocks, blk, 0, stream>>>(h1, offs, csr_pack, dis, W_h, b_h, h0);
    k_gmm<<<gmm_blocks, blk, 0, stream>>>(h0, offs, csr_pack, dis, W_out, b_out, h1);

    // MLP + pool
    k_mlp<<<gmm_blocks, blk, 0, stream>>>(h1, batch, fc1_w, fc1_b, fc2_w, fc2_b,
                                          fc3_w, fc3_b, sums);
    k_finish<<<(N_GRAPHS + 255) / 256, blk, 0, stream>>>(sums, batch, idx_a, idx_b,
                                                         out_pairs, out_util);
}

// Round 14
// 260.866 us; speedup vs baseline: 1.0568x; 1.0568x over previous
//
#include <hip/hip_runtime.h>
#include <math.h>

#define N_NODES  50000
#define N_EDGES  800000
#define N_GRAPHS 5000
#define N_PAIRS  4096
#define F_IN     9
#define H        64
#define NCHUNK   49   // ceil(50000/1024)
#define WPAD     68   // transposed-weight row stride: 272B = 16B-aligned

__device__ __forceinline__ float fast_tanh(float x) {
    float e = __expf(-2.0f * fabsf(x));
    float t = __fdividef(1.0f - e, 1.0f + e);
    return copysignf(t, x);
}

__device__ __forceinline__ float bf2f(unsigned short u) {
    union { unsigned int i; float f; } v; v.i = ((unsigned int)u) << 16; return v.f;
}
__device__ __forceinline__ unsigned short f2bf(float f) {
    union { float f; unsigned int i; } v; v.f = f;
    unsigned int u = v.i;
    return (unsigned short)((u + 0x7FFFu + ((u >> 16) & 1u)) >> 16);
}

__device__ __forceinline__ int lbound(const int* __restrict__ a, int n, int v) {
    int lo = 0, hi = n;
    while (lo < hi) { int m = (lo + hi) >> 1; if (a[m] < v) lo = m + 1; else hi = m; }
    return lo;
}

// ---------------- degree + per-edge rank (atomic return value IS the rank) --------

__global__ void k_deg_rank(const int* __restrict__ dst, int* __restrict__ degi,
                           unsigned char* __restrict__ rank) {
    int i = blockIdx.x * blockDim.x + threadIdx.x;
    if (i < N_EDGES) rank[i] = (unsigned char)atomicAdd(&degi[dst[i]], 1);
}

// ---------------- dis + xs = x*dis + chunk sums (merged) ----------------

__global__ void k_dis_chunksum(const int* __restrict__ degi, const float* __restrict__ x,
                               float* __restrict__ dis, float* __restrict__ xs,
                               int* __restrict__ chunksum) {
    __shared__ int wsum[4];
    int t = threadIdx.x, lane = t & 63, wi = t >> 6;
    int base_i = blockIdx.x * 1024 + t * 4;
    int s = 0;
#pragma unroll
    for (int k = 0; k < 4; ++k) {
        int i = base_i + k;
        if (i < N_NODES) {
            int dg = degi[i];
            s += dg;
            float d = rsqrtf((float)dg + 1.0f);
            dis[i] = d;
#pragma unroll
            for (int j = 0; j < F_IN; ++j) xs[i * F_IN + j] = x[i * F_IN + j] * d;
        }
    }
    for (int o = 32; o > 0; o >>= 1) s += __shfl_down(s, o, 64);
    if (lane == 0) wsum[wi] = s;
    __syncthreads();
    if (t == 0) chunksum[blockIdx.x] = wsum[0] + wsum[1] + wsum[2] + wsum[3];
}

__global__ void k_scanchunks(const int* __restrict__ chunksum, int* __restrict__ chunkbase,
                             int* __restrict__ off) {
    int lane = threadIdx.x;
    int v = (lane < NCHUNK) ? chunksum[lane] : 0;
    int inc = v;
    for (int o = 1; o < 64; o <<= 1) {
        int u = __shfl_up(inc, o, 64);
        if (lane >= o) inc += u;
    }
    if (lane < NCHUNK) chunkbase[lane] = inc - v;
    if (lane == 0) off[N_NODES] = N_EDGES;
}

__global__ void k_scan(const int* __restrict__ degi, const int* __restrict__ chunkbase,
                       int* __restrict__ off) {
    __shared__ int wsum[4];
    int t = threadIdx.x, lane = t & 63, wi = t >> 6;
    int base_i = blockIdx.x * 1024 + t * 4;
    int v[4];
    int s = 0;
#pragma unroll
    for (int k = 0; k < 4; ++k) {
        int i = base_i + k;
        v[k] = (i < N_NODES) ? degi[i] : 0;
        s += v[k];
    }
    int inc = s;
    for (int o = 1; o < 64; o <<= 1) {
        int u = __shfl_up(inc, o, 64);
        if (lane >= o) inc += u;
    }
    if (lane == 63) wsum[wi] = inc;
    __syncthreads();
    int wbase = 0;
    for (int w = 0; w < 4; ++w) if (w < wi) wbase += wsum[w];
    int ex = chunkbase[blockIdx.x] + wbase + inc - s;
#pragma unroll
    for (int k = 0; k < 4; ++k) {
        int i = base_i + k;
        if (i < N_NODES) off[i] = ex;
        ex += v[k];
    }
}

// CSR entry = u32 src byte-offset (src<<7). pos = off[dst]+rank, no atomic,
// 4B scattered store (norm is folded into activations).
__global__ void k_fill(const int* __restrict__ src, const int* __restrict__ dst,
                       const unsigned char* __restrict__ rank,
                       const int* __restrict__ off, unsigned int* __restrict__ csr32) {
    int e = blockIdx.x * blockDim.x + threadIdx.x;
    if (e < N_EDGES) {
        int d = dst[e];
        int pos = off[d] + (int)rank[e];
        csr32[pos] = (unsigned int)(src[e] << 7);
    }
}

// ---------------- layer 1 fused: agg xs (9-wide) -> *dis -> LDS -> mm+tanh*dis -------

__global__ __launch_bounds__(256) void k_layer1(
        const float* __restrict__ xs, const int* __restrict__ off,
        const unsigned int* __restrict__ csr32,
        const float* __restrict__ dis, const float* __restrict__ W,
        const float* __restrict__ b, unsigned short* __restrict__ h) {
    __shared__ float sW[F_IN * H];
    __shared__ float sb[H];
    __shared__ float sax[16][F_IN + 1];   // +1 pad
    __shared__ float sdis[16];
    for (int t = threadIdx.x; t < F_IN * H; t += 256) sW[t] = W[t];
    if (threadIdx.x < H) sb[threadIdx.x] = b[threadIdx.x];

    // phase 1: 16-lane group per node (lanes 0..8 active)
    int g = threadIdx.x >> 4, l = threadIdx.x & 15;
    int node = blockIdx.x * 16 + g;
    if (node < N_NODES && l < F_IN) {
        int beg = off[node], end = off[node + 1];
        float d = dis[node];
        float acc = xs[node * F_IN + l];       // self: dis*(xs_i + sum) needs xs_i here
        for (int e = beg; e < end; ++e) {
            int s = (int)(csr32[e] >> 7);
            acc += xs[s * F_IN + l];
        }
        sax[g][l] = acc * d;
        if (l == 0) sdis[g] = d;
    }
    __syncthreads();

    // phase 2: 4 rows per wave; output hs = tanh * dis (folded for next layer)
    int wi = threadIdx.x >> 6, j = threadIdx.x & 63;
    for (int r = 0; r < 4; ++r) {
        int row = blockIdx.x * 16 + wi * 4 + r;
        if (row >= N_NODES) break;
        float acc = sb[j];
#pragma unroll
        for (int k = 0; k < F_IN; ++k) acc += sax[wi * 4 + r][k] * sW[k * H + j];
        h[row * H + j] = f2bf(fast_tanh(acc) * sdis[wi * 4 + r]);
    }
}

// ---------------- fused layer: sum(hs) -> *dis -> @W + b -> tanh [*dis] -> bf16 -------
// R12 depth-2 pipeline on u32 entries; inner loop is pure {load, gather, add}.

__global__ __launch_bounds__(256) void k_gmm(
        const unsigned short* __restrict__ hin, const int* __restrict__ off,
        const unsigned int* __restrict__ csr32,
        const float* __restrict__ dis, const float* __restrict__ W,
        const float* __restrict__ b, unsigned short* __restrict__ hout,
        const int fold) {
    __shared__ float sWt[H][WPAD];   // sWt[j][k] = W[k][j]
    __shared__ float sb[H];
    __shared__ float srow[4][H];
    for (int t = threadIdx.x; t < H * H; t += 256) {
        int k = t >> 6, jx = t & 63;
        sWt[jx][k] = W[t];
    }
    if (threadIdx.x < H) sb[threadIdx.x] = b[threadIdx.x];
    __syncthreads();
    int wi = threadIdx.x >> 6, j = threadIdx.x & 63;
    const char* hbase = (const char*)hin + (j << 1);   // per-lane feature offset
    for (int it = 0; it < 8; ++it) {
        int node = blockIdx.x * 32 + wi * 8 + it;
        if (node >= N_NODES) break;
        int beg = off[node], end = off[node + 1];
        float d = dis[node];
        float acc = bf2f(hin[node * H + j]);   // self term: dis*(hs_i + sum)
        int nfull = (end - beg) >> 2;
        int e = beg + (nfull << 2);
        const unsigned int* cp = csr32 + beg;

        if (nfull >= 2) {
            unsigned int a0 = cp[0], a1 = cp[1], a2 = cp[2], a3 = cp[3];
            unsigned int b0 = cp[4], b1 = cp[5], b2 = cp[6], b3 = cp[7];
            float va0 = bf2f(*(const unsigned short*)(hbase + a0));
            float va1 = bf2f(*(const unsigned short*)(hbase + a1));
            float va2 = bf2f(*(const unsigned short*)(hbase + a2));
            float va3 = bf2f(*(const unsigned short*)(hbase + a3));
            for (int bi = 1; bi < nfull - 1; ++bi) {
                // gathers for gen b (addresses ready from last iteration)
                float vb0 = bf2f(*(const unsigned short*)(hbase + b0));
                float vb1 = bf2f(*(const unsigned short*)(hbase + b1));
                float vb2 = bf2f(*(const unsigned short*)(hbase + b2));
                float vb3 = bf2f(*(const unsigned short*)(hbase + b3));
                // prefetch entries for gen c
                const unsigned int* np = cp + ((bi + 1) << 2);
                unsigned int c0 = np[0], c1 = np[1], c2 = np[2], c3 = np[3];
                // accumulate gen a (gathers issued one iteration ago)
                acc += (va0 + va1) + (va2 + va3);
                a0 = b0; a1 = b1; a2 = b2; a3 = b3;
                va0 = vb0; va1 = vb1; va2 = vb2; va3 = vb3;
                b0 = c0; b1 = c1; b2 = c2; b3 = c3;
            }
            float vb0 = bf2f(*(const unsigned short*)(hbase + b0));
            float vb1 = bf2f(*(const unsigned short*)(hbase + b1));
            float vb2 = bf2f(*(const unsigned short*)(hbase + b2));
            float vb3 = bf2f(*(const unsigned short*)(hbase + b3));
            acc += (va0 + va1) + (va2 + va3);
            acc += (vb0 + vb1) + (vb2 + vb3);
        } else if (nfull == 1) {
            float v0 = bf2f(*(const unsigned short*)(hbase + cp[0]));
            float v1 = bf2f(*(const unsigned short*)(hbase + cp[1]));
            float v2 = bf2f(*(const unsigned short*)(hbase + cp[2]));
            float v3 = bf2f(*(const unsigned short*)(hbase + cp[3]));
            acc += (v0 + v1) + (v2 + v3);
        }
        for (; e < end; ++e)
            acc += bf2f(*(const unsigned short*)(hbase + csr32[e]));

        srow[wi][j] = acc * d;      // wave-local write then read: in-order per wave
        float a = sb[j];
#pragma unroll
        for (int kb = 0; kb < H; kb += 4) {
            float4 g4 = *(const float4*)&srow[wi][kb];   // uniform-addr broadcast
            float4 w4 = *(const float4*)&sWt[j][kb];     // per-lane b128
            a += g4.x * w4.x + g4.y * w4.y + g4.z * w4.z + g4.w * w4.w;
        }
        float t = fast_tanh(a);
        hout[node * H + j] = f2bf(fold ? t * d : t);
    }
}

// ---------------- fused MLP + graph pool ----------------

__global__ __launch_bounds__(256) void k_mlp(
        const unsigned short* __restrict__ h, const int* __restrict__ batch,
        const float* __restrict__ fc1w, const float* __restrict__ fc1b,
        const float* __restrict__ fc2w, const float* __restrict__ fc2b,
        const float* __restrict__ fc3w, const float* __restrict__ fc3b,
        float* __restrict__ sums) {
    __shared__ float s1t[H][WPAD];    // s1t[j][k] = fc1w[k*H+j]
    __shared__ float s2t[32][WPAD];   // s2t[j][k] = fc2w[k*32+j]
    __shared__ float s3[32];
    __shared__ float sb1[H];
    __shared__ float sb2[32];
    __shared__ float srow[4][H];
    __shared__ float s1out[4][H];

    for (int t = threadIdx.x; t < H * H; t += 256) {
        int k = t >> 6, jx = t & 63;
        s1t[jx][k] = fc1w[t];
    }
    for (int t = threadIdx.x; t < H * 32; t += 256) {
        int k = t >> 5, jx = t & 31;
        s2t[jx][k] = fc2w[t];
    }
    if (threadIdx.x < 32) s3[threadIdx.x] = fc3w[threadIdx.x];
    if (threadIdx.x < H)  sb1[threadIdx.x] = fc1b[threadIdx.x];
    if (threadIdx.x < 32) sb2[threadIdx.x] = fc2b[threadIdx.x];
    __syncthreads();

    int wi = threadIdx.x >> 6, j = threadIdx.x & 63;
    int jj = j & 31, kb0 = (j >> 5) << 5;
    float b3 = fc3b[0];

    for (int it = 0; it < 8; ++it) {
        int node = blockIdx.x * 32 + wi * 8 + it;
        if (node >= N_NODES) break;

        srow[wi][j] = bf2f(h[node * H + j]);

        float a1 = sb1[j];
#pragma unroll
        for (int kb = 0; kb < H; kb += 4) {
            float4 g4 = *(const float4*)&srow[wi][kb];
            float4 w4 = *(const float4*)&s1t[j][kb];
            a1 += g4.x * w4.x + g4.y * w4.y + g4.z * w4.z + g4.w * w4.w;
        }
        a1 = fast_tanh(a1);
        s1out[wi][j] = a1;

        float a2 = 0.f;
#pragma unroll
        for (int kb = 0; kb < 32; kb += 4) {
            float4 g4 = *(const float4*)&s1out[wi][kb0 + kb];
            float4 w4 = *(const float4*)&s2t[jj][kb0 + kb];
            a2 += g4.x * w4.x + g4.y * w4.y + g4.z * w4.z + g4.w * w4.w;
        }
        a2 += __shfl_xor(a2, 32);             // combine k-halves
        float val = fast_tanh(a2 + sb2[jj]) * s3[jj];
        for (int o = 16; o > 0; o >>= 1) val += __shfl_xor(val, o);
        if (j == 0) atomicAdd(&sums[batch[node]], val + b3);
    }
}

// ---------------- readout: util + pairs (cnt via binary search, merged) ----------------

__global__ void k_finish(const float* __restrict__ sums, const int* __restrict__ batch,
                         const int* __restrict__ ia, const int* __restrict__ ib,
                         float* __restrict__ out_pairs, float* __restrict__ out_util) {
    int i = blockIdx.x * blockDim.x + threadIdx.x;
    if (i < N_GRAPHS) {
        int c = lbound(batch, N_NODES, i + 1) - lbound(batch, N_NODES, i);
        out_util[i] = sums[i] / fmaxf((float)c, 1.0f);
    }
    if (i < N_PAIRS) {
        int a = ia[i], b = ib[i];
        int ca = lbound(batch, N_NODES, a + 1) - lbound(batch, N_NODES, a);
        int cb = lbound(batch, N_NODES, b + 1) - lbound(batch, N_NODES, b);
        float ua = sums[a] / fmaxf((float)ca, 1.0f);
        float ub = sums[b] / fmaxf((float)cb, 1.0f);
        out_pairs[i] = 1.0f / (1.0f + __expf(-(ub - ua)));
    }
}

// ---------------- launch ----------------

extern "C" void kernel_launch(void* const* d_in, const int* in_sizes, int n_in,
                              void* d_out, int out_size, void* d_ws, size_t ws_size,
                              hipStream_t stream) {
    const float* x     = (const float*)d_in[0];
    const int*   ei    = (const int*)d_in[1];
    const int*   batch = (const int*)d_in[2];
    const int*   idx_a = (const int*)d_in[3];
    const int*   idx_b = (const int*)d_in[4];
    const float* W_in  = (const float*)d_in[5];
    const float* b_in  = (const float*)d_in[6];
    const float* W_h   = (const float*)d_in[7];
    const float* b_h   = (const float*)d_in[8];
    const float* W_out = (const float*)d_in[9];
    const float* b_out = (const float*)d_in[10];
    const float* fc1_w = (const float*)d_in[11];
    const float* fc1_b = (const float*)d_in[12];
    const float* fc2_w = (const float*)d_in[13];
    const float* fc2_b = (const float*)d_in[14];
    const float* fc3_w = (const float*)d_in[15];
    const float* fc3_b = (const float*)d_in[16];

    const int* src = ei;
    const int* dst = ei + N_EDGES;

    char* wsb = (char*)d_ws;
    // zero-region (one memset): degi, sums
    int*   degi     = (int*)wsb;    wsb += N_NODES * 4;
    float* sums     = (float*)wsb;  wsb += N_GRAPHS * 4;
    float* dis      = (float*)wsb;  wsb += N_NODES * 4;
    float* xs       = (float*)wsb;  wsb += (size_t)N_NODES * F_IN * 4;
    unsigned short* h0 = (unsigned short*)wsb;  wsb += (size_t)N_NODES * H * 2;
    unsigned short* h1 = (unsigned short*)wsb;  wsb += (size_t)N_NODES * H * 2;
    int*   offs     = (int*)wsb;    wsb += (N_NODES + 1) * 4;
    int*   chunksum = (int*)wsb;    wsb += NCHUNK * 4;
    int*   chunkbase= (int*)wsb;    wsb += NCHUNK * 4;
    unsigned char* rank = (unsigned char*)wsb;  wsb += N_EDGES;
    wsb = (char*)(((size_t)wsb + 3) & ~(size_t)3);
    unsigned int* csr32 = (unsigned int*)wsb; wsb += (size_t)N_EDGES * 4;

    float* out_pairs = (float*)d_out;
    float* out_util  = out_pairs + N_PAIRS;

    hipMemsetAsync(degi, 0, (N_NODES + N_GRAPHS) * sizeof(int), stream);

    dim3 blk(256);
    k_deg_rank<<<(N_EDGES + 255) / 256, blk, 0, stream>>>(dst, degi, rank);
    k_dis_chunksum<<<NCHUNK, blk, 0, stream>>>(degi, x, dis, xs, chunksum);
    k_scanchunks<<<1, 64, 0, stream>>>(chunksum, chunkbase, offs);
    k_scan<<<NCHUNK, blk, 0, stream>>>(degi, chunkbase, offs);
    k_fill<<<(N_EDGES + 255) / 256, blk, 0, stream>>>(src, dst, rank, offs, csr32);

    // layer 1 fused: agg xs + mm_in, outputs hs (tanh*dis)
    k_layer1<<<(N_NODES + 15) / 16, blk, 0, stream>>>(xs, offs, csr32, dis, W_in, b_in, h0);

    const int gmm_blocks = (N_NODES + 31) / 32;
    // layers 2..4: fused sum+scale+matmul+bias+tanh (depth-2 pipelined)
    k_gmm<<<gmm_blocks, blk, 0, stream>>>(h0, offs, csr32, dis, W_h, b_h, h1, 1);
    k_gmm<<<gmm_blocks, blk, 0, stream>>>(h1, offs, csr32, dis, W_h, b_h, h0, 1);
    k_gmm<<<gmm_blocks, blk, 0, stream>>>(h0, offs, csr32, dis, W_out, b_out, h1, 0);

    // MLP + pool
    k_mlp<<<gmm_blocks, blk, 0, stream>>>(h1, batch, fc1_w, fc1_b, fc2_w, fc2_b,
                                          fc3_w, fc3_b, sums);
    k_finish<<<(N_GRAPHS + 255) / 256, blk, 0, stream>>>(sums, batch, idx_a, idx_b,
                                                         out_pairs, out_util);
}